// Round 7
// baseline (316.720 us; speedup 1.0000x reference)
//
#include <hip/hip_runtime.h>
#include <cfloat>
#include <cmath>

#define CCH 256   // channels
#define HID 16    // hidden = C / R

typedef float f32x4 __attribute__((ext_vector_type(4)));

// Round-2 fused kernel (285 us best) with ONE change: apply-phase stores are
// plain stores instead of __builtin_nontemporal_store (A/B test of the NT
// write path vs the 6.7 TB/s demonstrated by the harness fill kernel).
//   1. stream segment (float4, 2 rows in flight), sum+max per channel
//   2. LDS reduce -> avg/max pools
//   3. fused MLP: att = sigmoid((relu(avg@W1+b1)+relu(max@W1+b1))@W2 + 2*b2)
//   4. apply att to own segment in REVERSE order (re-read hits L2/L3)
__global__ __launch_bounds__(512) void fused_gca_kernel(
    const float* __restrict__ x, const int* __restrict__ seg,
    const int* __restrict__ numg,
    const float* __restrict__ W1, const float* __restrict__ b1,
    const float* __restrict__ W2, const float* __restrict__ b2,
    float* __restrict__ out, int N)
{
    const int G = *numg;
    const int tid = (int)threadIdx.x;
    const int c4  = tid & 63;   // lane: which float4 of the 256-ch row
    const int r   = tid >> 6;   // wave id 0..7 = row group

    __shared__ f32x4 lsum[512];
    __shared__ f32x4 lmax[512];
    __shared__ float pool2[2 * CCH];   // [0:256) avg, [256:512) max
    __shared__ float ht[2 * HID];
    __shared__ float attn[CCH];

    for (int g = (int)blockIdx.x; g < G; g += (int)gridDim.x) {
        // ---- segment bounds: lower_bound(g), lower_bound(g+1) ----
        int lo = 0, hi = N;
        while (lo < hi) { int mid = (lo + hi) >> 1; if (seg[mid] < g) lo = mid + 1; else hi = mid; }
        const int start = lo;
        hi = N;
        while (lo < hi) { int mid = (lo + hi) >> 1; if (seg[mid] <= g) lo = mid + 1; else hi = mid; }
        const int end = lo;
        const int count = end - start;

        // ---- phase 1: pooling stream (2 rows in flight per wave) ----
        f32x4 s = {0.f, 0.f, 0.f, 0.f};
        f32x4 m = {-FLT_MAX, -FLT_MAX, -FLT_MAX, -FLT_MAX};
        const float* xp = x + (size_t)c4 * 4;
        int n = start + r;
        for (; n + 8 < end; n += 16) {
            const f32x4 v0 = *reinterpret_cast<const f32x4*>(xp + (size_t)(n)     * CCH);
            const f32x4 v1 = *reinterpret_cast<const f32x4*>(xp + (size_t)(n + 8) * CCH);
            s += v0;
            m.x = fmaxf(m.x, v0.x); m.y = fmaxf(m.y, v0.y);
            m.z = fmaxf(m.z, v0.z); m.w = fmaxf(m.w, v0.w);
            s += v1;
            m.x = fmaxf(m.x, v1.x); m.y = fmaxf(m.y, v1.y);
            m.z = fmaxf(m.z, v1.z); m.w = fmaxf(m.w, v1.w);
        }
        if (n < end) {
            const f32x4 v0 = *reinterpret_cast<const f32x4*>(xp + (size_t)n * CCH);
            s += v0;
            m.x = fmaxf(m.x, v0.x); m.y = fmaxf(m.y, v0.y);
            m.z = fmaxf(m.z, v0.z); m.w = fmaxf(m.w, v0.w);
        }
        lsum[tid] = s; lmax[tid] = m;
        __syncthreads();

        // ---- phase 2: cross-wave reduce (64 threads own 4 channels each) ----
        if (tid < 64) {
            f32x4 S = lsum[tid];
            f32x4 M = lmax[tid];
            #pragma unroll
            for (int k = 1; k < 8; ++k) {
                const f32x4 S2 = lsum[tid + 64 * k];
                const f32x4 M2 = lmax[tid + 64 * k];
                S += S2;
                M.x = fmaxf(M.x, M2.x); M.y = fmaxf(M.y, M2.y);
                M.z = fmaxf(M.z, M2.z); M.w = fmaxf(M.w, M2.w);
            }
            const float inv = (count > 0) ? 1.0f / (float)count : 0.0f;
            pool2[4 * tid + 0] = S.x * inv;
            pool2[4 * tid + 1] = S.y * inv;
            pool2[4 * tid + 2] = S.z * inv;
            pool2[4 * tid + 3] = S.w * inv;
            pool2[CCH + 4 * tid + 0] = (count > 0) ? M.x : 0.0f;
            pool2[CCH + 4 * tid + 1] = (count > 0) ? M.y : 0.0f;
            pool2[CCH + 4 * tid + 2] = (count > 0) ? M.z : 0.0f;
            pool2[CCH + 4 * tid + 3] = (count > 0) ? M.w : 0.0f;
        }
        __syncthreads();

        // ---- phase 3a: hidden layer (16 threads per (pool,j) pair) ----
        {
            const int pair = tid >> 4;        // 0..31: pool = pair>>4, j = pair&15
            const int sub  = tid & 15;
            const int j    = pair & (HID - 1);
            const float* p = pool2 + (pair >> 4) * CCH;
            float h = 0.f;
            #pragma unroll
            for (int c = sub; c < CCH; c += 16)
                h = fmaf(p[c], W1[c * HID + j], h);
            h += __shfl_xor(h, 8, 64);
            h += __shfl_xor(h, 4, 64);
            h += __shfl_xor(h, 2, 64);
            h += __shfl_xor(h, 1, 64);
            if (sub == 0) ht[pair] = fmaxf(h + b1[j], 0.0f);
        }
        __syncthreads();

        // ---- phase 3b: output layer + sigmoid ----
        if (tid < CCH) {
            float acc = 2.0f * b2[tid];
            #pragma unroll
            for (int j = 0; j < HID; ++j)
                acc = fmaf(ht[j] + ht[HID + j], W2[j * CCH + tid], acc);
            attn[tid] = 1.0f / (1.0f + expf(-acc));
        }
        __syncthreads();

        // ---- phase 4: apply, reverse order for L2/L3 reuse, plain stores ----
        {
            const f32x4 a4 = *reinterpret_cast<const f32x4*>(attn + c4 * 4);
            const int rem = end - (start + r);
            if (rem > 0) {
                int k = ((rem + 7) >> 3) - 1;   // last row index for this wave
                const float* xq = x   + (size_t)(start + r) * CCH + (size_t)c4 * 4;
                float*       oq = out + (size_t)(start + r) * CCH + (size_t)c4 * 4;
                for (; k >= 1; k -= 2) {
                    const size_t i0 = (size_t)(k)     * (8 * CCH);
                    const size_t i1 = (size_t)(k - 1) * (8 * CCH);
                    const f32x4 v0 = *reinterpret_cast<const f32x4*>(xq + i0);
                    const f32x4 v1 = *reinterpret_cast<const f32x4*>(xq + i1);
                    *reinterpret_cast<f32x4*>(oq + i0) = v0 * a4;
                    *reinterpret_cast<f32x4*>(oq + i1) = v1 * a4;
                }
                if (k == 0) {
                    const f32x4 v0 = *reinterpret_cast<const f32x4*>(xq);
                    *reinterpret_cast<f32x4*>(oq) = v0 * a4;
                }
            }
        }
        __syncthreads();  // protect LDS reuse on next grid-stride iteration
    }
}

extern "C" void kernel_launch(void* const* d_in, const int* in_sizes, int n_in,
                              void* d_out, int out_size, void* d_ws, size_t ws_size,
                              hipStream_t stream) {
    const float* x    = (const float*)d_in[0];
    const int*   seg  = (const int*)d_in[1];   // sorted segment ids (int32)
    const int*   numg = (const int*)d_in[2];   // num_graphs scalar (device read)
    const float* W1   = (const float*)d_in[3]; // [C, H]
    const float* b1   = (const float*)d_in[4]; // [H]
    const float* W2   = (const float*)d_in[5]; // [H, C]
    const float* b2   = (const float*)d_in[6]; // [C]
    float* out = (float*)d_out;

    const int N = in_sizes[1];                 // number of nodes

    fused_gca_kernel<<<512, 512, 0, stream>>>(x, seg, numg, W1, b1, W2, b2, out, N);
}

// Round 8
// 300.756 us; speedup vs baseline: 1.0531x; 1.0531x over previous
//
#include <hip/hip_runtime.h>
#include <cfloat>
#include <cmath>

#define CCH 256   // channels
#define HID 16    // hidden = C / R

typedef float f32x4 __attribute__((ext_vector_type(4)));

__device__ __forceinline__ int lower_bound(const int* __restrict__ seg, int N, int v) {
    int lo = 0, hi = N;
    while (lo < hi) { int mid = (lo + hi) >> 1; if (seg[mid] < v) lo = mid + 1; else hi = mid; }
    return lo;
}

__device__ __forceinline__ void acc_row(const f32x4 v, f32x4& s, f32x4& m) {
    s += v;
    m.x = fmaxf(m.x, v.x); m.y = fmaxf(m.y, v.y);
    m.z = fmaxf(m.z, v.z); m.w = fmaxf(m.w, v.w);
}

// Stream rows base, base+STEP, ... < end (2 loads in flight), accumulating sum+max.
template<int STEP>
__device__ __forceinline__ void pool_rows(const float* __restrict__ xp, int base, int end,
                                          f32x4& s, f32x4& m) {
    int n = base;
    for (; n + STEP < end; n += 2 * STEP) {
        const f32x4 v0 = *reinterpret_cast<const f32x4*>(xp + (size_t)(n)        * CCH);
        const f32x4 v1 = *reinterpret_cast<const f32x4*>(xp + (size_t)(n + STEP) * CCH);
        acc_row(v0, s, m);
        acc_row(v1, s, m);
    }
    if (n < end) {
        const f32x4 v0 = *reinterpret_cast<const f32x4*>(xp + (size_t)n * CCH);
        acc_row(v0, s, m);
    }
}

// Apply attention to rows base, base+STEP, ... < end, walking TAIL->HEAD
// (LIFO: tail was pooled most recently -> L2/L3 hits). NT stores.
template<int STEP>
__device__ __forceinline__ void apply_rows(const float* __restrict__ x, float* __restrict__ out,
                                           const float* __restrict__ attn,
                                           int base, int end, int c4) {
    const f32x4 a4 = *reinterpret_cast<const f32x4*>(attn + c4 * 4);
    const int rem = end - base;
    if (rem <= 0) return;
    int k = (rem + STEP - 1) / STEP - 1;
    const float* xq = x   + (size_t)base * CCH + (size_t)c4 * 4;
    float*       oq = out + (size_t)base * CCH + (size_t)c4 * 4;
    for (; k >= 1; k -= 2) {
        const size_t i0 = (size_t)(k)     * (STEP * CCH);
        const size_t i1 = (size_t)(k - 1) * (STEP * CCH);
        const f32x4 v0 = *reinterpret_cast<const f32x4*>(xq + i0);
        const f32x4 v1 = *reinterpret_cast<const f32x4*>(xq + i1);
        __builtin_nontemporal_store(v0 * a4, reinterpret_cast<f32x4*>(oq + i0));
        __builtin_nontemporal_store(v1 * a4, reinterpret_cast<f32x4*>(oq + i1));
    }
    if (k == 0) {
        const f32x4 v0 = *reinterpret_cast<const f32x4*>(xq);
        __builtin_nontemporal_store(v0 * a4, reinterpret_cast<f32x4*>(oq));
    }
}

// Two-graph software pipeline per block (256 blocks x 1024 threads = 16 waves).
//   E1 : pool(g0), all 16 waves           [pure HBM read]
//   MLP(g0) -> attn0
//   E2 : waves 0-7 pool(g1) from HBM  ||  waves 8-15 apply(g0) reverse+NT
//        [mixes HBM reads, L3 reads, HBM writes chip-wide]
//   MLP(g1) -> attn1
//   E3 : apply(g1), all 16 waves, reverse+NT
__global__ __launch_bounds__(1024) void fused2_gca_kernel(
    const float* __restrict__ x, const int* __restrict__ seg,
    const int* __restrict__ numg,
    const float* __restrict__ W1, const float* __restrict__ b1,
    const float* __restrict__ W2, const float* __restrict__ b2,
    float* __restrict__ out, int N)
{
    const int G = *numg;
    const int tid = (int)threadIdx.x;
    const int c4  = tid & 63;   // lane: which float4 of the 256-ch row
    const int r   = tid >> 6;   // wave id 0..15

    __shared__ f32x4 lsum[1024];
    __shared__ f32x4 lmax[1024];
    __shared__ float pool2[2 * CCH];   // [0:256) avg, [256:512) max
    __shared__ float ht[2 * HID];
    __shared__ float attn0[CCH];
    __shared__ float attn1[CCH];

    const int GP = (G + 1) >> 1;       // graph pairs
    const float* xp = x + (size_t)c4 * 4;

    for (int gp = (int)blockIdx.x; gp < GP; gp += (int)gridDim.x) {
        const int g0 = 2 * gp;
        const int g1 = 2 * gp + 1;

        const int s0 = lower_bound(seg, N, g0);
        const int s1 = lower_bound(seg, N, g0 + 1);       // == end of g0
        const int e1 = (g1 < G) ? lower_bound(seg, N, g1 + 1) : s1;
        const int cnt0 = s1 - s0;
        const int cnt1 = e1 - s1;

        // ======== E1: pool g0 with all 16 waves (rows s0+r, step 16) ========
        {
            f32x4 s = {0.f, 0.f, 0.f, 0.f};
            f32x4 m = {-FLT_MAX, -FLT_MAX, -FLT_MAX, -FLT_MAX};
            pool_rows<16>(xp, s0 + r, s1, s, m);
            lsum[tid] = s; lmax[tid] = m;
        }
        __syncthreads();

        // reduce 16 groups -> pool2
        if (tid < 64) {
            f32x4 S = lsum[tid];
            f32x4 M = lmax[tid];
            #pragma unroll
            for (int k = 1; k < 16; ++k) {
                const f32x4 S2 = lsum[tid + 64 * k];
                const f32x4 M2 = lmax[tid + 64 * k];
                S += S2;
                M.x = fmaxf(M.x, M2.x); M.y = fmaxf(M.y, M2.y);
                M.z = fmaxf(M.z, M2.z); M.w = fmaxf(M.w, M2.w);
            }
            const float inv = (cnt0 > 0) ? 1.0f / (float)cnt0 : 0.0f;
            pool2[4 * tid + 0] = S.x * inv;
            pool2[4 * tid + 1] = S.y * inv;
            pool2[4 * tid + 2] = S.z * inv;
            pool2[4 * tid + 3] = S.w * inv;
            pool2[CCH + 4 * tid + 0] = (cnt0 > 0) ? M.x : 0.0f;
            pool2[CCH + 4 * tid + 1] = (cnt0 > 0) ? M.y : 0.0f;
            pool2[CCH + 4 * tid + 2] = (cnt0 > 0) ? M.z : 0.0f;
            pool2[CCH + 4 * tid + 3] = (cnt0 > 0) ? M.w : 0.0f;
        }
        __syncthreads();

        // MLP(g0) hidden: 512 threads, 16 per (pool,j) pair
        if (tid < 512) {
            const int pair = tid >> 4;
            const int sub  = tid & 15;
            const int j    = pair & (HID - 1);
            const float* p = pool2 + (pair >> 4) * CCH;
            float h = 0.f;
            #pragma unroll
            for (int c = sub; c < CCH; c += 16)
                h = fmaf(p[c], W1[c * HID + j], h);
            h += __shfl_xor(h, 8, 64);
            h += __shfl_xor(h, 4, 64);
            h += __shfl_xor(h, 2, 64);
            h += __shfl_xor(h, 1, 64);
            if (sub == 0) ht[pair] = fmaxf(h + b1[j], 0.0f);
        }
        __syncthreads();
        if (tid < CCH) {
            float acc = 2.0f * b2[tid];
            #pragma unroll
            for (int j = 0; j < HID; ++j)
                acc = fmaf(ht[j] + ht[HID + j], W2[j * CCH + tid], acc);
            attn0[tid] = 1.0f / (1.0f + expf(-acc));
        }
        __syncthreads();

        // ======== E2: waves 0-7 pool g1 (HBM) || waves 8-15 apply g0 ========
        if (r < 8) {
            f32x4 s = {0.f, 0.f, 0.f, 0.f};
            f32x4 m = {-FLT_MAX, -FLT_MAX, -FLT_MAX, -FLT_MAX};
            pool_rows<8>(xp, s1 + r, e1, s, m);
            lsum[tid] = s; lmax[tid] = m;
        } else {
            apply_rows<8>(x, out, attn0, s0 + (r - 8), s1, c4);
        }
        __syncthreads();

        // reduce 8 groups -> pool2
        if (tid < 64) {
            f32x4 S = lsum[tid];
            f32x4 M = lmax[tid];
            #pragma unroll
            for (int k = 1; k < 8; ++k) {
                const f32x4 S2 = lsum[tid + 64 * k];
                const f32x4 M2 = lmax[tid + 64 * k];
                S += S2;
                M.x = fmaxf(M.x, M2.x); M.y = fmaxf(M.y, M2.y);
                M.z = fmaxf(M.z, M2.z); M.w = fmaxf(M.w, M2.w);
            }
            const float inv = (cnt1 > 0) ? 1.0f / (float)cnt1 : 0.0f;
            pool2[4 * tid + 0] = S.x * inv;
            pool2[4 * tid + 1] = S.y * inv;
            pool2[4 * tid + 2] = S.z * inv;
            pool2[4 * tid + 3] = S.w * inv;
            pool2[CCH + 4 * tid + 0] = (cnt1 > 0) ? M.x : 0.0f;
            pool2[CCH + 4 * tid + 1] = (cnt1 > 0) ? M.y : 0.0f;
            pool2[CCH + 4 * tid + 2] = (cnt1 > 0) ? M.z : 0.0f;
            pool2[CCH + 4 * tid + 3] = (cnt1 > 0) ? M.w : 0.0f;
        }
        __syncthreads();

        // MLP(g1)
        if (tid < 512) {
            const int pair = tid >> 4;
            const int sub  = tid & 15;
            const int j    = pair & (HID - 1);
            const float* p = pool2 + (pair >> 4) * CCH;
            float h = 0.f;
            #pragma unroll
            for (int c = sub; c < CCH; c += 16)
                h = fmaf(p[c], W1[c * HID + j], h);
            h += __shfl_xor(h, 8, 64);
            h += __shfl_xor(h, 4, 64);
            h += __shfl_xor(h, 2, 64);
            h += __shfl_xor(h, 1, 64);
            if (sub == 0) ht[pair] = fmaxf(h + b1[j], 0.0f);
        }
        __syncthreads();
        if (tid < CCH) {
            float acc = 2.0f * b2[tid];
            #pragma unroll
            for (int j = 0; j < HID; ++j)
                acc = fmaf(ht[j] + ht[HID + j], W2[j * CCH + tid], acc);
            attn1[tid] = 1.0f / (1.0f + expf(-acc));
        }
        __syncthreads();

        // ======== E3: apply g1 with all 16 waves, reverse ========
        if (cnt1 > 0)
            apply_rows<16>(x, out, attn1, s1 + r, e1, c4);
        __syncthreads();   // protect LDS reuse on next grid-stride iteration
    }
}

extern "C" void kernel_launch(void* const* d_in, const int* in_sizes, int n_in,
                              void* d_out, int out_size, void* d_ws, size_t ws_size,
                              hipStream_t stream) {
    const float* x    = (const float*)d_in[0];
    const int*   seg  = (const int*)d_in[1];   // sorted segment ids (int32)
    const int*   numg = (const int*)d_in[2];   // num_graphs scalar (device read)
    const float* W1   = (const float*)d_in[3]; // [C, H]
    const float* b1   = (const float*)d_in[4]; // [H]
    const float* W2   = (const float*)d_in[5]; // [H, C]
    const float* b2   = (const float*)d_in[6]; // [C]
    float* out = (float*)d_out;

    const int N = in_sizes[1];                 // number of nodes

    fused2_gca_kernel<<<256, 1024, 0, stream>>>(x, seg, numg, W1, b1, W2, b2, out, N);
}